// Round 5
// baseline (268.627 us; speedup 1.0000x reference)
//
#include <hip/hip_runtime.h>
#include <hip/hip_bf16.h>
#include <stdint.h>

// PixproLoss: out = -(sum_masked cos_sim / count_mask), B=2048, C=256, P=49.
// m2[c,p] = sum_q (mask[p,q]*inv_nm[q]) * m[c,q]  (MFMA over q)
// num_b   = sum_p inv_nb[p] * sum_c b[c,p]*m2[c,p]
// R5: 512 blocks x 4 batches, software-pipelined; m-payload double-buffered across
// iterations; A/b issued at compute start, consumed phases later; LDS-only barriers
// (s_waitcnt lgkmcnt(0); s_barrier) keep global loads in flight across phases;
// ping-pong LDS buffers per batch parity.

typedef __attribute__((ext_vector_type(8))) short short8;
typedef __attribute__((ext_vector_type(4))) float floatx4;

#define P 49
#define CP 12544           // C*P
#define NMASK 2401         // P*P
#define MS_STRIDE 72
#define NB 4               // batches per block

__device__ __forceinline__ void barrier_lds_only() {
  // LDS producer->consumer ordering without draining in-flight global loads
  asm volatile("s_waitcnt lgkmcnt(0)\n\ts_barrier" ::: "memory");
}

__device__ __forceinline__ short8 cvt8(float4 a, float4 b) {
  union { __hip_bfloat162 h2; short s2[2]; } t;
  short8 r;
  t.h2 = __float22bfloat162_rn(make_float2(a.x, a.y)); r[0] = t.s2[0]; r[1] = t.s2[1];
  t.h2 = __float22bfloat162_rn(make_float2(a.z, a.w)); r[2] = t.s2[0]; r[3] = t.s2[1];
  t.h2 = __float22bfloat162_rn(make_float2(b.x, b.y)); r[4] = t.s2[0]; r[5] = t.s2[1];
  t.h2 = __float22bfloat162_rn(make_float2(b.z, b.w)); r[6] = t.s2[0]; r[7] = t.s2[1];
  return r;
}

__global__ __launch_bounds__(512) void pixpro_main(
    const float* __restrict__ base, const float* __restrict__ moment,
    const int* __restrict__ A, float* __restrict__ ws_num, float* __restrict__ ws_cnt)
{
  // ping-pong LDS (batch parity). ~35 KB total.
  __shared__ __align__(16) uint16_t maskS[2][P * MS_STRIDE];
  __shared__ __align__(16) float normred[2][32 * 64];
  __shared__ __align__(16) float nbred[2][32 * 16];
  __shared__ __align__(16) float inv_nm_s[2][64];
  __shared__ __align__(16) float inv_nb_s[2][64];

  const int tid  = threadIdx.x;
  const int lane = tid & 63;
  const int wv   = tid >> 6;
  const int mrow = lane & 15;
  const int kgrp = (lane >> 4) & 3;
  const int b0   = blockIdx.x * NB;

  const bool btask = tid < P * 8;
  const int  bp    = tid >> 3;
  const int  bqg   = tid & 7;
  const int  bq0   = bqg * 8;

  const int pbase[4] = {0, 16, 32, 33};

  // ---------------- m-payload (double-buffered) ----------------
  float4 pm[2][2][4];   // [buf][cti][{a0,a1,b0,b1}]

  #define ISSUE_M(BUF, BB)                                                   \
    {                                                                        \
      const float* gm_ = moment + (size_t)(BB) * CP;                         \
      _Pragma("unroll")                                                      \
      for (int cti = 0; cti < 2; ++cti) {                                    \
        const int c_ = (2 * wv + cti) * 16 + mrow;                           \
        const float* row_ = gm_ + c_ * P;                                    \
        pm[BUF][cti][0] = *(const float4*)(row_ + kgrp * 8);                 \
        pm[BUF][cti][1] = *(const float4*)(row_ + kgrp * 8 + 4);             \
        if (kgrp < 2) {                                                      \
          pm[BUF][cti][2] = *(const float4*)(row_ + 32 + kgrp * 8);          \
          pm[BUF][cti][3] = *(const float4*)(row_ + 32 + kgrp * 8 + 4);      \
        } else if (kgrp == 2) {                                              \
          pm[BUF][cti][2] = make_float4(row_[48], 0.f, 0.f, 0.f);            \
          pm[BUF][cti][3] = make_float4(0.f, 0.f, 0.f, 0.f);                 \
        } else {                                                             \
          pm[BUF][cti][2] = make_float4(0.f, 0.f, 0.f, 0.f);                 \
          pm[BUF][cti][3] = make_float4(0.f, 0.f, 0.f, 0.f);                 \
        }                                                                    \
      }                                                                      \
    }

  ISSUE_M(0, b0);   // prologue

  #pragma unroll
  for (int s = 0; s < NB; ++s) {
    const int buf = s & 1;
    const int bb  = b0 + s;
    const float* gb = base + (size_t)bb * CP;
    const int*   gA = A    + (size_t)bb * NMASK;

    // ---- issue A(s) and b(s): consumed 1-3 barrier-phases later ----
    int4 pA0 = make_int4(0, 0, 0, 0), pA1 = make_int4(0, 0, 0, 0);
    int  pA2 = 0;
    if (btask) {
      const int* Ar = gA + bp * P + bq0;
      if (bqg <= 5)      { pA0 = *(const int4*)Ar; pA1 = *(const int4*)(Ar + 4); }
      else if (bqg == 6) { pA2 = Ar[0]; }
    }
    float bv[2][4][4];
    #pragma unroll
    for (int cti = 0; cti < 2; ++cti)
      #pragma unroll
      for (int pt = 0; pt < 4; ++pt) {
        const int pd = pbase[pt] + mrow;
        #pragma unroll
        for (int r = 0; r < 4; ++r) {
          const int c = (2 * wv + cti) * 16 + kgrp * 4 + r;
          bv[cti][pt][r] = gb[c * P + pd];
        }
      }

    // ---- issue m(s+1) into the other buffer (stays in flight across all barriers) ----
    if (s + 1 < NB) { ISSUE_M(buf ^ 1, bb + 1); }

    // ---- phase A: cvt m(s) -> afrag, m-norm partials -> normred[buf] ----
    short8 afrag[2][2];
    float s0[8], s1[8];
    #pragma unroll
    for (int j = 0; j < 8; ++j) { s0[j] = 0.f; s1[j] = 0.f; }
    #pragma unroll
    for (int cti = 0; cti < 2; ++cti) {
      float4 a0 = pm[buf][cti][0], a1 = pm[buf][cti][1];
      float4 c0 = pm[buf][cti][2], c1 = pm[buf][cti][3];
      s0[0] = fmaf(a0.x, a0.x, s0[0]); s0[1] = fmaf(a0.y, a0.y, s0[1]);
      s0[2] = fmaf(a0.z, a0.z, s0[2]); s0[3] = fmaf(a0.w, a0.w, s0[3]);
      s0[4] = fmaf(a1.x, a1.x, s0[4]); s0[5] = fmaf(a1.y, a1.y, s0[5]);
      s0[6] = fmaf(a1.z, a1.z, s0[6]); s0[7] = fmaf(a1.w, a1.w, s0[7]);
      s1[0] = fmaf(c0.x, c0.x, s1[0]); s1[1] = fmaf(c0.y, c0.y, s1[1]);
      s1[2] = fmaf(c0.z, c0.z, s1[2]); s1[3] = fmaf(c0.w, c0.w, s1[3]);
      s1[4] = fmaf(c1.x, c1.x, s1[4]); s1[5] = fmaf(c1.y, c1.y, s1[5]);
      s1[6] = fmaf(c1.z, c1.z, s1[6]); s1[7] = fmaf(c1.w, c1.w, s1[7]);
      afrag[cti][0] = cvt8(a0, a1);
      afrag[cti][1] = cvt8(c0, c1);
    }
    #pragma unroll
    for (int j = 0; j < 8; ++j) {
      s0[j] += __shfl_xor(s0[j], 1); s0[j] += __shfl_xor(s0[j], 2);
      s1[j] += __shfl_xor(s1[j], 1); s1[j] += __shfl_xor(s1[j], 2);
    }
    if ((lane & 3) == 0) {
      const int h = mrow >> 2;
      float* nr = &normred[buf][(wv * 4 + h) * 64 + kgrp * 8];
      *(float4*)(nr + 0)  = make_float4(s0[0], s0[1], s0[2], s0[3]);
      *(float4*)(nr + 4)  = make_float4(s0[4], s0[5], s0[6], s0[7]);
      *(float4*)(nr + 32) = make_float4(s1[0], s1[1], s1[2], s1[3]);
      *(float4*)(nr + 36) = make_float4(s1[4], s1[5], s1[6], s1[7]);
    }
    barrier_lds_only();   // barrier 1

    // ---- phase B: wave0 finalizes inv_nm; ALL waves write b-norm partials ----
    if (tid < 64) {
      float s_ = 0.f;
      #pragma unroll
      for (int wh = 0; wh < 32; ++wh) s_ += normred[buf][wh * 64 + tid];
      inv_nm_s[buf][tid] = 1.0f / fmaxf(sqrtf(s_), 1e-6f);
    }
    {
      float sq[4];
      #pragma unroll
      for (int pt = 0; pt < 4; ++pt) {
        float s_ = 0.f;
        #pragma unroll
        for (int cti = 0; cti < 2; ++cti)
          #pragma unroll
          for (int r = 0; r < 4; ++r) {
            float f = bv[cti][pt][r];
            if (pt == 3 && mrow != 15) f = 0.f;   // dedup tile 3 (rows 33..47 dup tile 2)
            s_ = fmaf(f, f, s_);
          }
        s_ += __shfl_xor(s_, 16); s_ += __shfl_xor(s_, 32);
        sq[pt] = s_;
      }
      if (lane < 16) {
        #pragma unroll
        for (int pt = 0; pt < 4; ++pt) nbred[buf][(wv * 4 + pt) * 16 + mrow] = sq[pt];
      }
    }
    barrier_lds_only();   // barrier 2

    // ---- phase C: maskS build (tid<392) using inv_nm; wave7 finalizes inv_nb ----
    int cntpart = 0;
    if (btask) {
      int bm[8];
      bm[0] = pA0.x; bm[1] = pA0.y; bm[2] = pA0.z; bm[3] = pA0.w;
      bm[4] = pA1.x; bm[5] = pA1.y; bm[6] = pA1.z; bm[7] = pA1.w;
      if (bqg == 6) { bm[0] = pA2; bm[1] = bm[2] = bm[3] = bm[4] = bm[5] = bm[6] = bm[7] = 0; }
      if (bqg == 7) { bm[0] = bm[1] = bm[2] = bm[3] = bm[4] = bm[5] = bm[6] = bm[7] = 0; }
      float4 i0 = *(const float4*)&inv_nm_s[buf][bq0];
      float4 i1 = *(const float4*)&inv_nm_s[buf][bq0 + 4];
      float4 f0, f1;
      f0.x = bm[0] ? i0.x : 0.f; f0.y = bm[1] ? i0.y : 0.f;
      f0.z = bm[2] ? i0.z : 0.f; f0.w = bm[3] ? i0.w : 0.f;
      f1.x = bm[4] ? i1.x : 0.f; f1.y = bm[5] ? i1.y : 0.f;
      f1.z = bm[6] ? i1.z : 0.f; f1.w = bm[7] ? i1.w : 0.f;
      #pragma unroll
      for (int j = 0; j < 8; ++j) cntpart += bm[j];
      *(short8*)&maskS[buf][bp * MS_STRIDE + bq0] = cvt8(f0, f1);
    } else if (tid >= 448) {
      const int p = tid - 448;
      if (p < P) {
        const int pt = (p == 48) ? 3 : (p >> 4);
        const int mr = (p == 48) ? 15 : (p & 15);
        float s_ = 0.f;
        #pragma unroll
        for (int w = 0; w < 8; ++w) s_ += nbred[buf][(w * 4 + pt) * 16 + mr];
        inv_nb_s[buf][p] = 1.0f / fmaxf(sqrtf(s_), 1e-6f);
      }
    }
    barrier_lds_only();   // barrier 3

    // ---- phase D: MFMA + epilogue ----
    float inb[4];
    #pragma unroll
    for (int pt = 0; pt < 4; ++pt) inb[pt] = inv_nb_s[buf][pbase[pt] + mrow];

    floatx4 acc[2][4];
    #pragma unroll
    for (int i = 0; i < 2; ++i)
      #pragma unroll
      for (int j = 0; j < 4; ++j) acc[i][j] = (floatx4){0.f, 0.f, 0.f, 0.f};
    #pragma unroll
    for (int kt = 0; kt < 2; ++kt) {
      short8 bfr[4];
      #pragma unroll
      for (int pt = 0; pt < 4; ++pt)
        bfr[pt] = *(const short8*)&maskS[buf][(pbase[pt] + mrow) * MS_STRIDE + kt * 32 + kgrp * 8];
      #pragma unroll
      for (int cti = 0; cti < 2; ++cti)
        #pragma unroll
        for (int pt = 0; pt < 4; ++pt)
          acc[cti][pt] = __builtin_amdgcn_mfma_f32_16x16x32_bf16(afrag[cti][kt], bfr[pt], acc[cti][pt], 0, 0, 0);
    }

    float num = 0.f;
    #pragma unroll
    for (int pt = 0; pt < 4; ++pt) {
      float tmp = 0.f;
      #pragma unroll
      for (int cti = 0; cti < 2; ++cti)
        #pragma unroll
        for (int r = 0; r < 4; ++r) {
          float f = bv[cti][pt][r];
          if (pt == 3 && mrow != 15) f = 0.f;
          tmp = fmaf(f, acc[cti][pt][r], tmp);
        }
      num = fmaf(inb[pt], tmp, num);
    }
    float cntf = (float)cntpart;
    #pragma unroll
    for (int off = 32; off > 0; off >>= 1) {
      num  += __shfl_xor(num, off);
      cntf += __shfl_xor(cntf, off);
    }
    if (lane == 0) {
      ws_num[bb * 8 + wv] = num;
      ws_cnt[bb * 8 + wv] = cntf;
    }
    // no trailing barrier: next batch writes the OTHER LDS buffer, and waves
    // can't drift more than one barrier apart.
  }
  #undef ISSUE_M
}

__global__ __launch_bounds__(512) void pixpro_reduce(
    const float* __restrict__ ws_num, const float* __restrict__ ws_cnt,
    float* __restrict__ out)
{
  __shared__ float rn[8], rc[8];
  float n = 0.f, c = 0.f;
  for (int i = threadIdx.x; i < 16384; i += 512) { n += ws_num[i]; c += ws_cnt[i]; }
  #pragma unroll
  for (int off = 32; off > 0; off >>= 1) {
    n += __shfl_xor(n, off);
    c += __shfl_xor(c, off);
  }
  const int wv = threadIdx.x >> 6, lane = threadIdx.x & 63;
  if (lane == 0) { rn[wv] = n; rc[wv] = c; }
  __syncthreads();
  if (threadIdx.x == 0) {
    float N = 0.f, D = 0.f;
    #pragma unroll
    for (int i = 0; i < 8; ++i) { N += rn[i]; D += rc[i]; }
    out[0] = -(N / D);
  }
}

extern "C" void kernel_launch(void* const* d_in, const int* in_sizes, int n_in,
                              void* d_out, int out_size, void* d_ws, size_t ws_size,
                              hipStream_t stream) {
  const float* base   = (const float*)d_in[0];
  const float* moment = (const float*)d_in[1];
  const int*   A      = (const int*)d_in[2];
  float* ws_num = (float*)d_ws;            // 16384 floats
  float* ws_cnt = ws_num + 16384;          // 16384 floats
  pixpro_main<<<512, 512, 0, stream>>>(base, moment, A, ws_num, ws_cnt);
  pixpro_reduce<<<1, 512, 0, stream>>>(ws_num, ws_cnt, (float*)d_out);
}